// Round 9
// baseline (259.444 us; speedup 1.0000x reference)
//
#include <hip/hip_runtime.h>

#define IN_DIM 128
#define OUT_DIM 64
#define PADK 136     // gemm LDS row stride for W^T (bf16 elems)
#define ZB 256       // out-zeroing blocks fused ahead of the gemm blocks

typedef float f32x4 __attribute__((ext_vector_type(4)));
typedef short bf16x8 __attribute__((ext_vector_type(8)));

__device__ __forceinline__ unsigned short f2bf(float f) {   // RNE f32->bf16
    unsigned u = __float_as_uint(f);
    return (unsigned short)((u + 0x7FFFu + ((u >> 16) & 1u)) >> 16);
}
__device__ __forceinline__ float bf2f(unsigned short h) {
    return __uint_as_float((unsigned)h << 16);
}

// ---------------------------------------------------------------------------
// GEMM body: xw(bf16) = x@W via split-bf16 MFMA (lo*hi + hi*lo + hi*hi),
// 64 rows/block.  A fragments loaded DIRECTLY from global x (per-lane
// contiguous 8 floats -> 2x float4), hi/lo-split in registers.  LDS holds
// only W^T hi/lo (34 KB) -> 4 blocks/CU (measured r3: occupancy 8.4% -> 36%).
// ---------------------------------------------------------------------------
__device__ __forceinline__ void gemm_body(const float* __restrict__ x,
                                          const float* __restrict__ w,
                                          unsigned short* __restrict__ xwb,
                                          int N, int blk,
                                          unsigned short* lds) {
    unsigned short* Bhi = lds;                 // W^T: [c][k], 17 KB each
    unsigned short* Blo = lds + 64 * PADK;

    const int t = threadIdx.x;
    const int r0 = blk * 64;

    {   // stage W^T hi/lo (W is 32 KB, L2-hot across blocks)
        const int c = t >> 2;
        const int kb = (t & 3) * 32;
        for (int k4 = 0; k4 < 32; k4 += 4) {
            ushort4 h, l;
            float v0 = w[(kb + k4 + 0) * OUT_DIM + c];
            float v1 = w[(kb + k4 + 1) * OUT_DIM + c];
            float v2 = w[(kb + k4 + 2) * OUT_DIM + c];
            float v3 = w[(kb + k4 + 3) * OUT_DIM + c];
            h.x = f2bf(v0); l.x = f2bf(v0 - bf2f(h.x));
            h.y = f2bf(v1); l.y = f2bf(v1 - bf2f(h.y));
            h.z = f2bf(v2); l.z = f2bf(v2 - bf2f(h.z));
            h.w = f2bf(v3); l.w = f2bf(v3 - bf2f(h.w));
            *(ushort4*)&Bhi[c * PADK + kb + k4] = h;
            *(ushort4*)&Blo[c * PADK + kb + k4] = l;
        }
    }

    const int lane = t & 63;
    const int wv = t >> 6;
    const int m = lane & 15;
    const int quad = lane >> 4;

    // A fragments: direct global loads, hi/lo split in registers.
    int row = r0 + wv * 16 + m; if (row >= N) row = N - 1;
    const float4* xr = (const float4*)(x + (size_t)row * IN_DIM);
    bf16x8 ahi[4], alo[4];
#pragma unroll
    for (int ks = 0; ks < 4; ++ks) {
        const float4 v0 = xr[ks * 8 + quad * 2];
        const float4 v1 = xr[ks * 8 + quad * 2 + 1];
        float f[8] = {v0.x, v0.y, v0.z, v0.w, v1.x, v1.y, v1.z, v1.w};
        bf16x8 h8, l8;
#pragma unroll
        for (int i = 0; i < 8; ++i) {
            const unsigned short h = f2bf(f[i]);
            h8[i] = (short)h;
            l8[i] = (short)f2bf(f[i] - bf2f(h));
        }
        ahi[ks] = h8; alo[ks] = l8;
    }
    __syncthreads();   // B staged

#pragma unroll
    for (int ct = 0; ct < 4; ++ct) {
        f32x4 acc = {0.f, 0.f, 0.f, 0.f};
#pragma unroll
        for (int ks = 0; ks < 4; ++ks) {
            const int off = (ct * 16 + m) * PADK + ks * 32 + quad * 8;
            bf16x8 bh = *(const bf16x8*)&Bhi[off];
            bf16x8 bl = *(const bf16x8*)&Blo[off];
            acc = __builtin_amdgcn_mfma_f32_16x16x32_bf16(alo[ks], bh, acc, 0, 0, 0);
            acc = __builtin_amdgcn_mfma_f32_16x16x32_bf16(ahi[ks], bl, acc, 0, 0, 0);
            acc = __builtin_amdgcn_mfma_f32_16x16x32_bf16(ahi[ks], bh, acc, 0, 0, 0);
        }
#pragma unroll
        for (int i = 0; i < 4; ++i) {
            const int r = r0 + wv * 16 + quad * 4 + i;
            if (r < N) xwb[(size_t)r * OUT_DIM + ct * 16 + m] = f2bf(acc[i]);
        }
    }
}

// ---------------------------------------------------------------------------
// K1: blocks [0,ZB) zero `out` (float4 grid-stride, overlaps the gemm);
// blocks [ZB, ZB+GB) run the GEMM.  34 KB LDS -> 4 blocks/CU.
// ---------------------------------------------------------------------------
__global__ __launch_bounds__(256) void gemm_zero(
        const float* __restrict__ x, const float* __restrict__ w,
        unsigned short* __restrict__ xwb, int N,
        float* __restrict__ out, int n4out) {
    __shared__ unsigned short LB[2 * 64 * PADK];   // 34 KB (gemm branch only)
    if ((int)blockIdx.x < ZB) {
        float4* o4 = (float4*)out;
        const f32x4 z = {0.f, 0.f, 0.f, 0.f};
        for (int i = blockIdx.x * 256 + threadIdx.x; i < n4out; i += ZB * 256)
            *(f32x4*)&o4[i] = z;
    } else {
        gemm_body(x, w, xwb, N, blockIdx.x - ZB, LB);
    }
}

// ---------------------------------------------------------------------------
// K2 scatter4: the whole binned pipeline (payload round-trip + 2 LDS sorts +
// cursor machinery, ~80us across r1-r8 regardless of structure) replaced by
// direct fire-and-forget global fp32 atomics.  Per iteration: 4 wave-uniform
// scalar edge loads (broadcast), 4 independent coalesced 128 B xwb gathers
// (xwb = 6.4 MB -> L2/LLC resident), 4 independent 64-lane atomic adds
// (256 B RMW, no return value -> no waitcnt dependency).  unsafeAtomicAdd
// emits the NATIVE fp32 atomic (r6 lesson: plain atomicAdd(float*) may CAS;
// the native-op requirement is explicit here).
// ---------------------------------------------------------------------------
__global__ __launch_bounds__(256) void scatter4(
        const int* __restrict__ arow, const int* __restrict__ acol,
        const float* __restrict__ aval, const unsigned short* __restrict__ xwb,
        float* __restrict__ out, int E) {
    const int lane = threadIdx.x & 63;
    const int gw = (int)((blockIdx.x * 256 + threadIdx.x) >> 6);
    const int nw = (int)((gridDim.x * 256) >> 6);
    const int E4 = E & ~3;

    for (int e = gw * 4; e < E4; e += nw * 4) {
        const int   r0 = arow[e],     r1 = arow[e + 1];
        const int   r2 = arow[e + 2], r3 = arow[e + 3];
        const int   c0 = acol[e],     c1 = acol[e + 1];
        const int   c2 = acol[e + 2], c3 = acol[e + 3];
        const float v0 = aval[e],     v1 = aval[e + 1];
        const float v2 = aval[e + 2], v3 = aval[e + 3];
        const float g0 = bf2f(xwb[(size_t)c0 * OUT_DIM + lane]);
        const float g1 = bf2f(xwb[(size_t)c1 * OUT_DIM + lane]);
        const float g2 = bf2f(xwb[(size_t)c2 * OUT_DIM + lane]);
        const float g3 = bf2f(xwb[(size_t)c3 * OUT_DIM + lane]);
        unsafeAtomicAdd(&out[(size_t)r0 * OUT_DIM + lane], v0 * g0);
        unsafeAtomicAdd(&out[(size_t)r1 * OUT_DIM + lane], v1 * g1);
        unsafeAtomicAdd(&out[(size_t)r2 * OUT_DIM + lane], v2 * g2);
        unsafeAtomicAdd(&out[(size_t)r3 * OUT_DIM + lane], v3 * g3);
    }
    // tail (E % 4 edges): first few waves take one each
    const int rem = E - E4;
    if (gw < rem) {
        const int e = E4 + gw;
        const float g = bf2f(xwb[(size_t)acol[e] * OUT_DIM + lane]);
        unsafeAtomicAdd(&out[(size_t)arow[e] * OUT_DIM + lane], aval[e] * g);
    }
}

// ---------------------------------------------------------------------------
// K3: fused ReLU pass over out (atomic accumulation must complete first).
// ---------------------------------------------------------------------------
__global__ __launch_bounds__(256) void relu_inplace(float* __restrict__ o, int n4) {
    float4* p = (float4*)o;
    int i = blockIdx.x * 256 + threadIdx.x;
    const int stride = gridDim.x * 256;
    for (; i < n4; i += stride) {
        float4 v = p[i];
        v.x = v.x > 0.f ? v.x : 0.f;
        v.y = v.y > 0.f ? v.y : 0.f;
        v.z = v.z > 0.f ? v.z : 0.f;
        v.w = v.w > 0.f ? v.w : 0.f;
        p[i] = v;
    }
}

static inline size_t align256(size_t x) { return (x + 255) & ~(size_t)255; }

extern "C" void kernel_launch(void* const* d_in, const int* in_sizes, int n_in,
                              void* d_out, int out_size, void* d_ws, size_t ws_size,
                              hipStream_t stream) {
    const float* x    = (const float*)d_in[0];
    const float* w    = (const float*)d_in[1];
    const int*   arow = (const int*)d_in[2];
    const int*   acol = (const int*)d_in[3];
    const float* aval = (const float*)d_in[4];
    float*       out  = (float*)d_out;

    const int N  = in_sizes[0] / IN_DIM;   // 50000
    const int E  = in_sizes[2];            // 800000
    const int GB = (N + 63) / 64;          // gemm blocks

    unsigned short* xwb = (unsigned short*)d_ws;   // 6.4 MB, ws is ~268 MB

    // K1: zero out (ZB blocks) overlapped with gemm (GB blocks)
    gemm_zero<<<ZB + GB, 256, 0, stream>>>(x, w, xwb, N, out, out_size / 4);
    // K2: direct atomic scatter (edges -> out), 8 blocks/CU
    scatter4<<<2048, 256, 0, stream>>>(arow, acol, aval, xwb, out, E);
    // K3: relu
    relu_inplace<<<2048, 256, 0, stream>>>(out, out_size / 4);
}

// Round 10
// 122.287 us; speedup vs baseline: 2.1216x; 2.1216x over previous
//
#include <hip/hip_runtime.h>

#define IN_DIM 128
#define OUT_DIM 64
#define PADK 136     // gemm LDS row stride (bf16 elems)
#define RB 64        // rows per bucket
#define RBSH 6       // log2(RB)
#define CAPB 1280    // bucket capacity (mean 1024, sigma 32 -> +8 sigma)
#define AB2 256      // afill blocks (fused: <= 1 per CU, overlap with gemm)

typedef float f32x4 __attribute__((ext_vector_type(4)));
typedef short bf16x8 __attribute__((ext_vector_type(8)));

__device__ __forceinline__ unsigned short f2bf(float f) {   // RNE f32->bf16
    unsigned u = __float_as_uint(f);
    return (unsigned short)((u + 0x7FFFu + ((u >> 16) & 1u)) >> 16);
}
__device__ __forceinline__ float bf2f(unsigned short h) {
    return __uint_as_float((unsigned)h << 16);
}

// ---------------------------------------------------------------------------
// GEMM body: xw(bf16) = x@W via split-bf16 MFMA (hi*hi + hi*lo + lo*hi),
// 64 rows/block.  LDS passed in (aliased with afill branch in fused kernel).
// r1-proven configuration (124.7 us session best).
// ---------------------------------------------------------------------------
__device__ __forceinline__ void gemm_body(const float* __restrict__ x,
                                          const float* __restrict__ w,
                                          unsigned short* __restrict__ xwb,
                                          int N, int blk,
                                          unsigned short* lds) {
    unsigned short* Ahi = lds;                 // 4 x 17 KB = 68 KB total
    unsigned short* Alo = lds + 64 * PADK;
    unsigned short* Bhi = lds + 2 * 64 * PADK; // W^T: [c][k]
    unsigned short* Blo = lds + 3 * 64 * PADK;

    const int t = threadIdx.x;
    const int r0 = blk * 64;

    {   // stage W^T hi/lo
        const int c = t >> 2;
        const int kb = (t & 3) * 32;
        for (int k4 = 0; k4 < 32; k4 += 4) {
            ushort4 h, l;
            float v0 = w[(kb + k4 + 0) * OUT_DIM + c];
            float v1 = w[(kb + k4 + 1) * OUT_DIM + c];
            float v2 = w[(kb + k4 + 2) * OUT_DIM + c];
            float v3 = w[(kb + k4 + 3) * OUT_DIM + c];
            h.x = f2bf(v0); l.x = f2bf(v0 - bf2f(h.x));
            h.y = f2bf(v1); l.y = f2bf(v1 - bf2f(h.y));
            h.z = f2bf(v2); l.z = f2bf(v2 - bf2f(h.z));
            h.w = f2bf(v3); l.w = f2bf(v3 - bf2f(h.w));
            *(ushort4*)&Bhi[c * PADK + kb + k4] = h;
            *(ushort4*)&Blo[c * PADK + kb + k4] = l;
        }
    }
    {   // stage x rows hi/lo
        const float4* x4 = (const float4*)x;
        for (int i = 0; i < 8; ++i) {
            const int f = i * 256 + t;
            const int rr = f >> 5;
            const int kk = (f & 31) * 4;
            int row = r0 + rr; if (row >= N) row = N - 1;
            float4 v = x4[(size_t)row * (IN_DIM / 4) + (kk >> 2)];
            ushort4 h, l;
            h.x = f2bf(v.x); l.x = f2bf(v.x - bf2f(h.x));
            h.y = f2bf(v.y); l.y = f2bf(v.y - bf2f(h.y));
            h.z = f2bf(v.z); l.z = f2bf(v.z - bf2f(h.z));
            h.w = f2bf(v.w); l.w = f2bf(v.w - bf2f(h.w));
            *(ushort4*)&Ahi[rr * PADK + kk] = h;
            *(ushort4*)&Alo[rr * PADK + kk] = l;
        }
    }
    __syncthreads();

    const int lane = t & 63;
    const int wv = t >> 6;
    const int m = lane & 15;
    const int quad = lane >> 4;

    bf16x8 ahi[4], alo[4];
#pragma unroll
    for (int ks = 0; ks < 4; ++ks) {
        const int off = (wv * 16 + m) * PADK + ks * 32 + quad * 8;
        ahi[ks] = *(const bf16x8*)&Ahi[off];
        alo[ks] = *(const bf16x8*)&Alo[off];
    }
#pragma unroll
    for (int ct = 0; ct < 4; ++ct) {
        f32x4 acc = {0.f, 0.f, 0.f, 0.f};
#pragma unroll
        for (int ks = 0; ks < 4; ++ks) {
            const int off = (ct * 16 + m) * PADK + ks * 32 + quad * 8;
            bf16x8 bh = *(const bf16x8*)&Bhi[off];
            bf16x8 bl = *(const bf16x8*)&Blo[off];
            acc = __builtin_amdgcn_mfma_f32_16x16x32_bf16(alo[ks], bh, acc, 0, 0, 0);
            acc = __builtin_amdgcn_mfma_f32_16x16x32_bf16(ahi[ks], bl, acc, 0, 0, 0);
            acc = __builtin_amdgcn_mfma_f32_16x16x32_bf16(ahi[ks], bh, acc, 0, 0, 0);
        }
#pragma unroll
        for (int i = 0; i < 4; ++i) {
            const int row = r0 + wv * 16 + quad * 4 + i;
            if (row < N) xwb[(size_t)row * OUT_DIM + ct * 16 + m] = f2bf(acc[i]);
        }
    }
}

// ---------------------------------------------------------------------------
// afill body: 3-pass GROUPED bucketing.  LDS histogram -> one global cursor
// claim per (block,bucket) -> grouped stores in ~4-8 edge runs.  4-wide
// vectorized loads for MLP.  word0 = col | rowLocal<<16, word1 = fp32 val.
// (r3: single-pass per-row scatter = 57.5 MB write-allocate blowup;
//  r9: global fp32 atomics = 200 MB write-through.  This structure wins.)
// ---------------------------------------------------------------------------
__device__ __forceinline__ void afill_body(
        const int* __restrict__ arow, const int* __restrict__ acol,
        const float* __restrict__ aval, int* __restrict__ pcur,
        int* __restrict__ ocount, uint4* __restrict__ olist,
        uint2* __restrict__ payload, int E, int NB, int chunk, int blk,
        int* ldsi) {
    int* cnt  = ldsi;          // [1024]
    int* base = ldsi + 1024;   // [1024]   (8 KB total, aliased into gemm LDS)
    const int t = threadIdx.x;
    const int lo = blk * chunk;            // chunk % 4 == 0 -> 16B aligned
    const int hi = min(E, lo + chunk);
    if (lo >= hi) return;
    const int len = hi - lo;
    const int n4  = len >> 2;
    const int4*   ar4 = (const int4*)(arow + lo);
    const int4*   ac4 = (const int4*)(acol + lo);
    const float4* av4 = (const float4*)(aval + lo);

    for (int i = t; i < NB; i += 256) cnt[i] = 0;
    __syncthreads();

    // pass 1: count, 4-wide
    for (int j = t; j < n4; j += 256) {
        const int4 r = ar4[j];
        atomicAdd(&cnt[r.x >> RBSH], 1);
        atomicAdd(&cnt[r.y >> RBSH], 1);
        atomicAdd(&cnt[r.z >> RBSH], 1);
        atomicAdd(&cnt[r.w >> RBSH], 1);
    }
    for (int e = lo + (n4 << 2) + t; e < hi; e += 256)
        atomicAdd(&cnt[arow[e] >> RBSH], 1);
    __syncthreads();

    // pass 2: claim one global cursor range per (block,bucket)
    for (int i = t; i < NB; i += 256) {
        const int c = cnt[i];
        base[i] = c ? atomicAdd(&pcur[i], c) : 0;
        cnt[i] = 0;
    }
    __syncthreads();

    // pass 3: grouped scatter, 4-wide
#define AF_EMIT(RR, CC, VV) do {                                              \
        const int b_ = (RR) >> RBSH;                                          \
        const int slot_ = base[b_] + atomicAdd(&cnt[b_], 1);                  \
        const unsigned w0_ = (unsigned)(CC) |                                 \
                             ((unsigned)((RR) & (RB - 1)) << 16);             \
        const unsigned w1_ = __float_as_uint(VV);                             \
        if (slot_ < CAPB) {                                                   \
            payload[(size_t)b_ * CAPB + slot_] = make_uint2(w0_, w1_);        \
        } else {                                                              \
            const int oi_ = atomicAdd(ocount, 1);                             \
            olist[oi_] = make_uint4((unsigned)(RR), (unsigned)(CC), w1_, 0u); \
        }                                                                     \
    } while (0)

    for (int j = t; j < n4; j += 256) {
        const int4   r = ar4[j];
        const int4   c = ac4[j];
        const float4 v = av4[j];
        AF_EMIT(r.x, c.x, v.x);
        AF_EMIT(r.y, c.y, v.y);
        AF_EMIT(r.z, c.z, v.z);
        AF_EMIT(r.w, c.w, v.w);
    }
    for (int e = lo + (n4 << 2) + t; e < hi; e += 256)
        AF_EMIT(arow[e], acol[e], aval[e]);
#undef AF_EMIT
}

// ---------------------------------------------------------------------------
// K1 fused: blocks [0,AB2) run afill (first in grid -> scheduling round 0,
// overlaps the gemm); blocks [AB2, AB2+GB) run the GEMM.  afill's 8 KB LDS
// is aliased into the gemm's 68 KB buffer (branch-disjoint).
// ---------------------------------------------------------------------------
__global__ __launch_bounds__(256) void gemm_afill(
        const float* __restrict__ x, const float* __restrict__ w,
        unsigned short* __restrict__ xwb, int N,
        const int* __restrict__ arow, const int* __restrict__ acol,
        const float* __restrict__ aval, int* __restrict__ pcur,
        int* __restrict__ ocount, uint4* __restrict__ olist,
        uint2* __restrict__ payload, int E, int NB, int chunk) {
    __shared__ unsigned short LB[4 * 64 * PADK];   // 68 KB, shared by branches
    if ((int)blockIdx.x < AB2) {
        afill_body(arow, acol, aval, pcur, ocount, olist, payload, E, NB,
                   chunk, blockIdx.x, (int*)LB);
    } else {
        gemm_body(x, w, xwb, N, blockIdx.x - AB2, LB);
    }
}

__global__ __launch_bounds__(256) void gemm_only(const float* __restrict__ x,
                                                 const float* __restrict__ w,
                                                 unsigned short* __restrict__ xwb,
                                                 int N) {
    __shared__ unsigned short LB[4 * 64 * PADK];
    gemm_body(x, w, xwb, N, blockIdx.x, LB);
}

// ---------------------------------------------------------------------------
// bagg3: block b owns rows [64b, 64b+64).  Int-LDS counting sort by local
// row (wave-parallel shfl scan), then wave wv pulls rows [8wv, 8wv+8) with
// 8-edge-ILP coalesced 128 B bf16 xw gathers.  Fused ReLU.
// ---------------------------------------------------------------------------
__global__ __launch_bounds__(512) void bagg3(
        const int* __restrict__ pcur, const uint2* __restrict__ payload,
        const unsigned short* __restrict__ xwb, float* __restrict__ out, int N,
        const int* __restrict__ ocount, const uint4* __restrict__ olist) {
    __shared__ uint2 stage[CAPB];       // 10 KB
    __shared__ int bins[RB + 1];
    __shared__ int pl[RB];
    const int t = threadIdx.x;
    const int lane = t & 63;
    const int wv = t >> 6;              // 0..7
    const int b = blockIdx.x;
    const int r0 = b << RBSH;

    const int cnt = min(pcur[b], CAPB); // payload filled contiguously [0,cnt)
    if (t <= RB) bins[t] = 0;
    if (t < RB) pl[t] = 0;
    __syncthreads();

    const uint2* pay = payload + (size_t)b * CAPB;
    for (int i = t; i < cnt; i += 512)
        atomicAdd(&bins[(pay[i].x >> 16) & (RB - 1)], 1);
    __syncthreads();
    if (t < RB) {                       // wave-parallel exclusive scan, 64 bins
        const int v = bins[t];
        int s = v;
#pragma unroll
        for (int d = 1; d < RB; d <<= 1) {
            const int u = __shfl_up(s, d, 64);
            if (t >= d) s += u;
        }
        bins[t + 1] = s;                // inclusive -> shifted = exclusive
        if (t == 0) bins[0] = 0;
    }
    __syncthreads();
    for (int i = t; i < cnt; i += 512) {
        const uint2 e = pay[i];
        const int rl = (e.x >> 16) & (RB - 1);
        stage[bins[rl] + atomicAdd(&pl[rl], 1)] = e;
    }
    __syncthreads();

    float acc[8];
#pragma unroll
    for (int lr = 0; lr < 8; ++lr) {
        const int row = wv * 8 + lr;
        int j = bins[row];
        const int end = bins[row + 1];
        float a0 = 0.f, a1 = 0.f;
        for (; j + 8 <= end; j += 8) {
            uint2 e0 = stage[j],   e1 = stage[j+1], e2 = stage[j+2], e3 = stage[j+3];
            uint2 e4 = stage[j+4], e5 = stage[j+5], e6 = stage[j+6], e7 = stage[j+7];
            float g0 = bf2f(xwb[(size_t)(e0.x & 0xFFFF) * OUT_DIM + lane]);
            float g1 = bf2f(xwb[(size_t)(e1.x & 0xFFFF) * OUT_DIM + lane]);
            float g2 = bf2f(xwb[(size_t)(e2.x & 0xFFFF) * OUT_DIM + lane]);
            float g3 = bf2f(xwb[(size_t)(e3.x & 0xFFFF) * OUT_DIM + lane]);
            float g4 = bf2f(xwb[(size_t)(e4.x & 0xFFFF) * OUT_DIM + lane]);
            float g5 = bf2f(xwb[(size_t)(e5.x & 0xFFFF) * OUT_DIM + lane]);
            float g6 = bf2f(xwb[(size_t)(e6.x & 0xFFFF) * OUT_DIM + lane]);
            float g7 = bf2f(xwb[(size_t)(e7.x & 0xFFFF) * OUT_DIM + lane]);
            a0 = fmaf(__uint_as_float(e0.y), g0, a0);
            a1 = fmaf(__uint_as_float(e1.y), g1, a1);
            a0 = fmaf(__uint_as_float(e2.y), g2, a0);
            a1 = fmaf(__uint_as_float(e3.y), g3, a1);
            a0 = fmaf(__uint_as_float(e4.y), g4, a0);
            a1 = fmaf(__uint_as_float(e5.y), g5, a1);
            a0 = fmaf(__uint_as_float(e6.y), g6, a0);
            a1 = fmaf(__uint_as_float(e7.y), g7, a1);
        }
        for (; j + 4 <= end; j += 4) {
            uint2 e0 = stage[j], e1 = stage[j+1], e2 = stage[j+2], e3 = stage[j+3];
            float g0 = bf2f(xwb[(size_t)(e0.x & 0xFFFF) * OUT_DIM + lane]);
            float g1 = bf2f(xwb[(size_t)(e1.x & 0xFFFF) * OUT_DIM + lane]);
            float g2 = bf2f(xwb[(size_t)(e2.x & 0xFFFF) * OUT_DIM + lane]);
            float g3 = bf2f(xwb[(size_t)(e3.x & 0xFFFF) * OUT_DIM + lane]);
            a0 = fmaf(__uint_as_float(e0.y), g0, a0);
            a1 = fmaf(__uint_as_float(e1.y), g1, a1);
            a0 = fmaf(__uint_as_float(e2.y), g2, a0);
            a1 = fmaf(__uint_as_float(e3.y), g3, a1);
        }
        for (; j < end; ++j) {
            uint2 e0 = stage[j];
            a0 = fmaf(__uint_as_float(e0.y),
                      bf2f(xwb[(size_t)(e0.x & 0xFFFF) * OUT_DIM + lane]), a0);
        }
        acc[lr] = a0 + a1;
    }

    // overflow contributions (oc == 0 in practice; one uniform load)
    const int oc = *ocount;
    for (int i = 0; i < oc; ++i) {
        const uint4 e = olist[i];
        const int lr = (int)e.x - r0 - wv * 8;
        if (lr >= 0 && lr < 8)
            acc[lr] += __uint_as_float(e.z) *
                       bf2f(xwb[(size_t)e.y * OUT_DIM + lane]);
    }

#pragma unroll
    for (int lr = 0; lr < 8; ++lr) {
        const int row = r0 + wv * 8 + lr;
        if (row < N) {
            const float v = acc[lr];
            out[(size_t)row * OUT_DIM + lane] = v > 0.f ? v : 0.f;
        }
    }
}

// ---------------------------------------------------------------------------
// Fallback: gemm + atomic scatter + relu (always correct).
// ---------------------------------------------------------------------------
__global__ __launch_bounds__(256) void scatter_edges(
        const int* __restrict__ arow, const int* __restrict__ acol,
        const float* __restrict__ aval, const unsigned short* __restrict__ xwb,
        float* __restrict__ out, int E) {
    const int lane = threadIdx.x & 63;
    int gw = (blockIdx.x * 256 + (int)threadIdx.x) >> 6;
    const int nw = (gridDim.x * 256) >> 6;
    for (int e = gw; e < E; e += nw) {
        const float m = aval[e] * bf2f(xwb[(size_t)acol[e] * OUT_DIM + lane]);
        atomicAdd(&out[(size_t)arow[e] * OUT_DIM + lane], m);
    }
}

__global__ __launch_bounds__(256) void relu_inplace(float* __restrict__ o, int n4) {
    float4* p = (float4*)o;
    int i = blockIdx.x * 256 + threadIdx.x;
    const int stride = gridDim.x * 256;
    for (; i < n4; i += stride) {
        float4 v = p[i];
        v.x = v.x > 0.f ? v.x : 0.f;
        v.y = v.y > 0.f ? v.y : 0.f;
        v.z = v.z > 0.f ? v.z : 0.f;
        v.w = v.w > 0.f ? v.w : 0.f;
        p[i] = v;
    }
}

static inline size_t align256(size_t x) { return (x + 255) & ~(size_t)255; }

extern "C" void kernel_launch(void* const* d_in, const int* in_sizes, int n_in,
                              void* d_out, int out_size, void* d_ws, size_t ws_size,
                              hipStream_t stream) {
    const float* x    = (const float*)d_in[0];
    const float* w    = (const float*)d_in[1];
    const int*   arow = (const int*)d_in[2];
    const int*   acol = (const int*)d_in[3];
    const float* aval = (const float*)d_in[4];
    float*       out  = (float*)d_out;

    const int N  = in_sizes[0] / IN_DIM;   // 50000
    const int E  = in_sizes[2];            // 800000
    const int NB = (N + RB - 1) >> RBSH;   // 782
    const int GB = (N + 63) / 64;          // gemm blocks

    char* ws = (char*)d_ws;
    const size_t szXW  = align256((size_t)N * OUT_DIM * sizeof(unsigned short));
    const size_t szCnt = align256((size_t)(NB + 1) * sizeof(int));   // pcur + ocount
    const size_t szOl  = align256((size_t)E * sizeof(uint4));        // olist sized E
    const size_t szPay = (size_t)NB * CAPB * sizeof(uint2);
    const size_t need0 = szXW + szCnt + szOl + szPay;

    unsigned short* xwb = (unsigned short*)ws;
    int*   pcur    = (int*)(ws + szXW);
    int*   ocount  = pcur + NB;
    uint4* olist   = (uint4*)(ws + szXW + szCnt);
    uint2* payload = (uint2*)(ws + szXW + szCnt + szOl);

    if (ws_size >= need0 && N <= 65536 && NB <= 1024) {
        (void)hipMemsetAsync(pcur, 0, (size_t)(NB + 1) * sizeof(int), stream);
        // chunk rounded up to a multiple of 4 so per-block int4/float4 loads
        // stay 16B-aligned (lo*4 % 16 == 0).
        const int chunk = (((E + AB2 - 1) / AB2) + 3) & ~3;
        gemm_afill<<<AB2 + GB, 256, 0, stream>>>(x, w, xwb, N, arow, acol, aval,
                                                 pcur, ocount, olist, payload,
                                                 E, NB, chunk);
        bagg3<<<NB, 512, 0, stream>>>(pcur, payload, xwb, out, N, ocount, olist);
    } else {
        gemm_only<<<GB, 256, 0, stream>>>(x, w, xwb, N);
        (void)hipMemsetAsync(d_out, 0, (size_t)out_size * sizeof(float), stream);
        scatter_edges<<<4096, 256, 0, stream>>>(arow, acol, aval, xwb, out, E);
        relu_inplace<<<2048, 256, 0, stream>>>(out, out_size / 4);
    }
}